// Round 18
// baseline (241.313 us; speedup 1.0000x reference)
//
#include <hip/hip_runtime.h>
#include <math.h>

#define B_C   4096   // comments
#define N_SRT 8192   // srt rows
#define D_C   768
#define D_S   1024
#define KSEL  2
#define NGRP  (N_SRT / 4)   // 2048 groups of 4 consecutive srt rows
#define PGRP  4             // groups refined per comment row (16 candidates)

typedef float    f32x4  __attribute__((ext_vector_type(4)));
typedef short    short8 __attribute__((ext_vector_type(8)));
typedef _Float16 half8  __attribute__((ext_vector_type(8)));

__device__ inline unsigned short f2bf(float f) {           // RTNE float->bf16
    unsigned u = __float_as_uint(f);
    u += 0x7FFF + ((u >> 16) & 1);
    return (unsigned short)(u >> 16);
}
__device__ inline float bf2f(unsigned short h) {
    return __uint_as_float(((unsigned)h) << 16);
}

#define GLOAD_LDS16(gsrc, ldst)                                                     \
    __builtin_amdgcn_global_load_lds(                                               \
        (const __attribute__((address_space(1))) void*)(gsrc),                      \
        (__attribute__((address_space(3))) void*)(ldst), 16, 0, 0)

// counted-vmcnt barrier pieces
#define WAIT_VM4  asm volatile("s_waitcnt vmcnt(4)" ::: "memory")
#define WAIT_VM2  asm volatile("s_waitcnt vmcnt(2)" ::: "memory")
#define WAIT_VM0  asm volatile("s_waitcnt vmcnt(0)" ::: "memory")
#define WAIT_LGKM asm volatile("s_waitcnt lgkmcnt(0)" ::: "memory")

// ---------------------------------------------------------------------------
// split_all: act split + weight split in ONE launch (round-16 verified).
// ---------------------------------------------------------------------------
#define NS_ACT ((N_SRT * D_S / 8 + B_C * D_C / 8) / 256)   // 5632

__global__ __launch_bounds__(256)
void split_all(const float* __restrict__ srt, const float* __restrict__ com,
               _Float16* __restrict__ pS, _Float16* __restrict__ pC,
               const float* __restrict__ Ws, _Float16* __restrict__ WtS,
               const float* __restrict__ Wc, _Float16* __restrict__ WtC) {
    __shared__ float t[64][65];
    if ((int)blockIdx.x < NS_ACT) {
        const int g = blockIdx.x * 256 + threadIdx.x;
        const int E0 = N_SRT * D_S / 8;
        const float* src;
        _Float16* dst;
        size_t stride;
        if (g < E0) {
            src = srt + (size_t)g * 8; dst = pS + (size_t)g * 8;
            stride = (size_t)N_SRT * D_S;
        } else {
            const int g2 = g - E0;
            src = com + (size_t)g2 * 8; dst = pC + (size_t)g2 * 8;
            stride = (size_t)B_C * D_C;
        }
        const float4 a = *reinterpret_cast<const float4*>(src);
        const float4 b = *reinterpret_cast<const float4*>(src + 4);
        const float x[8] = {a.x, a.y, a.z, a.w, b.x, b.y, b.z, b.w};
        half8 hv, mv;
#pragma unroll
        for (int j = 0; j < 8; ++j) {
            const _Float16 h = (_Float16)x[j];
            const float    r = x[j] - (float)h;          // exact
            hv[j] = h; mv[j] = (_Float16)(r * 2048.0f);
        }
        *reinterpret_cast<half8*>(dst)          = hv;
        *reinterpret_cast<half8*>(dst + stride) = mv;
    } else {
        const int bb = (int)blockIdx.x - NS_ACT;
        const bool p1 = bb >= 256;
        const int  b  = p1 ? bb - 256 : bb;
        const float* __restrict__ W = p1 ? Wc : Ws;
        _Float16* __restrict__ Wt   = p1 ? WtC : WtS;
        const int K  = p1 ? D_C : D_S;
        const int n0 = (b & 15) * 64, k0 = (b >> 4) * 64;

        const int tid = threadIdx.x;
        const int c = tid & 63, rq = tid >> 6;
#pragma unroll
        for (int j = 0; j < 16; ++j) {
            const int kr = rq * 16 + j;
            t[kr][c] = W[(size_t)(k0 + kr) * D_S + n0 + c];
        }
        __syncthreads();
        const size_t PS = (size_t)K * D_S;
#pragma unroll
        for (int j = 0; j < 16; ++j) {
            const int nr = rq * 16 + j;
            const float xs = t[c][nr] * 32768.0f;        // exact (pow2 scale)
            const _Float16 h = (_Float16)xs;
            const float    r = xs - (float)h;            // exact
            const size_t o = (size_t)(n0 + nr) * K + k0 + c;
            Wt[o]      = h;
            Wt[o + PS] = (_Float16)(r * 2048.0f);
        }
    }
}

// ---------------------------------------------------------------------------
// transform_8ph (round-18): both transforms via the r15-verified 8-phase
// half-tile schedule, expanded-K fp16x3. Tile 128(act rows) x 256(wt cols),
// BK=64, 512 threads (8 waves = 4 wt-64-blocks x 2 act-64-halves), wave-tile
// 64x64 (acc 4x4). LDS 96KB: sW[par][half] 16KB (128 wt rows x 64k),
// sAct[par][half] 8KB (64 act rows x 64k). K' = 3K tiles: pp0 = W0*(2048*A0),
// pp1 = W0*A1, pp2 = W1*A0, all at scale 2^26 (r7-verified numerics).
// Staging slot table (per parity, ph0..3): {Wnext h0, Wnext h1, Anext h0,
// Anext h1}; counted vmcnt(2) at each parity's ph3 retires exactly the 6
// gload instrs (W-half=2, act-half=1) the next parity reads; tail drains
// vmcnt(0). Hazards: every buffer overwrite is >=2 barriers after its last
// read's lgkm-retire (same argument as r15, which passed).
// Grid: 256 srt blocks + 128 com blocks = 384 (1 block/CU, good packing).
// ---------------------------------------------------------------------------
__global__ __launch_bounds__(512)
void transform_8ph(const _Float16* __restrict__ actS,
                   const _Float16* __restrict__ wtS,
                   const float* __restrict__ bS,
                   float* __restrict__ CS, unsigned short* __restrict__ HS,
                   const _Float16* __restrict__ actC,
                   const _Float16* __restrict__ wtC,
                   const float* __restrict__ bC,
                   float* __restrict__ CC, unsigned short* __restrict__ HC) {
    __shared__ __align__(16) _Float16 sW[2][2][128 * 64];   // [parity][half]
    __shared__ __align__(16) _Float16 sAct[2][2][64 * 64];  // [parity][half]
    const int tid  = threadIdx.x;
    const int lane = tid & 63;
    const int w    = tid >> 6;           // 0..7
    const int mw2  = w >> 1;             // wt 64-block 0..3
    const int nb   = w & 1;              // act 64-half
    const int mh   = mw2 >> 1;           // sW half this wave reads
    const int lr   = lane & 15, lg = lane >> 4;

    const int hw = blockIdx.x;
    int lgid, seg;
    if (hw < 256) { seg = 0; lgid = (hw & 7) * 32 + (hw >> 3); }
    else          { const int h2 = hw - 256; seg = 1; lgid = (h2 & 7) * 16 + (h2 >> 3); }

    const _Float16* __restrict__ actP = seg ? actC : actS;
    const _Float16* __restrict__ wtP  = seg ? wtC  : wtS;
    const float* __restrict__ bias    = seg ? bC   : bS;
    float* __restrict__ C             = seg ? CC   : CS;
    unsigned short* __restrict__ H    = seg ? HC   : HS;
    const int K    = seg ? D_C : D_S;
    const int NT   = seg ? 36 : 48;      // 3 * (K/64) K-tiles
    const int NIT  = NT >> 1;
    const size_t aps = seg ? (size_t)B_C * D_C : (size_t)N_SRT * D_S;
    const size_t wps = (size_t)D_S * K;

    const int bn = (lgid & 3) * 256;     // wt col tile
    const int m0 = (lgid >> 2) * 128;    // act row tile

    auto ppOf = [&](int tt) { return seg ? ((tt >= 12) + (tt >= 24)) : (tt >> 4); };
    auto kbOf = [&](int tt, int pp) { return seg ? (tt - pp * 12) * 64 : ((tt & 15) * 64); };

    const f32x4 vzero = {0.f, 0.f, 0.f, 0.f};
    f32x4 acc[4][4];
#pragma unroll
    for (int i = 0; i < 4; ++i)
#pragma unroll
        for (int j = 0; j < 4; ++j) acc[i][j] = vzero;

    // W half-tile: 128 rows x 64k = 1024 slots; 2 gloads/thread.
    auto stageW = [&](int buf, int half, int tt) {
        const int pp = ppOf(tt); const int kb = kbOf(tt, pp);
        const _Float16* g = wtP + (pp == 2 ? wps : 0)
                          + (size_t)(bn + half * 128) * K + kb;
#pragma unroll
        for (int i = 0; i < 2; ++i) {
            const int idx = tid + i * 512;
            const int r   = idx >> 3;
            const int sw  = ((idx & 7) ^ (r & 7)) * 8;
            GLOAD_LDS16(g + (size_t)r * K + sw,
                        (char*)&sW[buf][half][0] + idx * 16);
        }
    };
    // act half-tile: 64 rows x 64k = 512 slots; 1 gload/thread.
    auto stageA = [&](int buf, int half, int tt) {
        const int pp = ppOf(tt); const int kb = kbOf(tt, pp);
        const _Float16* g = actP + (pp == 1 ? aps : 0)
                          + (size_t)(m0 + half * 64) * K + kb;
        const int idx = tid;
        const int r   = idx >> 3;
        const int sw  = ((idx & 7) ^ (r & 7)) * 8;
        GLOAD_LDS16(g + (size_t)r * K + sw,
                    (char*)&sAct[buf][half][0] + idx * 16);
    };

    // prologue: tile0 W+act (6 instr), tile1 act (2 instr)
    stageW(0, 0, 0); stageW(0, 1, 0);
    stageA(0, 0, 0); stageA(0, 1, 0);
    stageA(1, 0, 1); stageA(1, 1, 1);
    WAIT_VM2;                            // tile0's 6 retired; act1 in flight
    __builtin_amdgcn_s_barrier();

    for (int it = 0; it < NIT; ++it) {
        const bool nl = (it + 1 < NIT);
#pragma unroll
        for (int par = 0; par < 2; ++par) {
            const int tt = 2 * it + par;
            const bool sc = (ppOf(tt) == 0);   // pp0: scale act frags by 2^11
            half8 bfr[4][2];
#pragma unroll
            for (int ph = 0; ph < 4; ++ph) {
                // ---- ds reads ----
                half8 afr[2];
                if (ph == 0) {
#pragma unroll
                    for (int j = 0; j < 4; ++j) {
                        const int rb = j * 16 + lr;
#pragma unroll
                        for (int ks = 0; ks < 2; ++ks)
                            bfr[j][ks] = *(const half8*)(
                                (const char*)&sAct[par][nb][0] + rb * 128 +
                                (((ks * 4 + lg) ^ (rb & 7)) * 16));
                    }
                    if (sc) {
#pragma unroll
                        for (int j = 0; j < 4; ++j)
#pragma unroll
                            for (int ks = 0; ks < 2; ++ks)
                                bfr[j][ks] = bfr[j][ks] * (_Float16)2048.0f;
                    }
                }
                {
                    const int ra = (mw2 & 1) * 64 + ph * 16 + lr;
#pragma unroll
                    for (int ks = 0; ks < 2; ++ks)
                        afr[ks] = *(const half8*)(
                            (const char*)&sW[par][mh][0] + ra * 128 +
                            (((ks * 4 + lg) ^ (ra & 7)) * 16));
                }
                // ---- stage one half-tile (slot table) ----
                if (par == 0) {
                    if (ph == 0)            stageW(1, 0, tt + 1);
                    else if (ph == 1)       stageW(1, 1, tt + 1);
                    else if (ph == 2) { if (nl) stageA(0, 0, tt + 2); }
                    else              { if (nl) stageA(0, 1, tt + 2); }
                } else {
                    if (ph == 0)      { if (nl) stageW(0, 0, tt + 1); }
                    else if (ph == 1) { if (nl) stageW(0, 1, tt + 1); }
                    else if (ph == 2) { if (nl) stageA(1, 0, tt + 2); }
                    else              { if (nl) stageA(1, 1, tt + 2); }
                }
                // ---- counted vmcnt at parity end ----
                if (ph == 3) { if (nl) { WAIT_VM2; } else { WAIT_VM0; } }
                __builtin_amdgcn_s_barrier();
                WAIT_LGKM;
                __builtin_amdgcn_s_setprio(1);
#pragma unroll
                for (int j = 0; j < 4; ++j)
#pragma unroll
                    for (int ks = 0; ks < 2; ++ks)
                        acc[ph][j] = __builtin_amdgcn_mfma_f32_16x16x32_f16(
                            afr[ks], bfr[j][ks], acc[ph][j], 0, 0, 0);
                __builtin_amdgcn_s_setprio(0);
                __builtin_amdgcn_s_barrier();
            }
        }
    }

    // epilogue: n = bn + mw2*64 + i*16 + lg*4 + q;  m = m0 + nb*64 + j*16 + lr
    const float s2 = 1.4901161193847656e-8f;    // 2^-26
#pragma unroll
    for (int i = 0; i < 4; ++i) {
        const int n = bn + mw2 * 64 + i * 16 + lg * 4;
        const f32x4 bb = *reinterpret_cast<const f32x4*>(&bias[n]);
#pragma unroll
        for (int j = 0; j < 4; ++j) {
            const int m = m0 + nb * 64 + j * 16 + lr;
            f32x4 o;
#pragma unroll
            for (int q = 0; q < 4; ++q)
                o[q] = fmaxf(fmaf(acc[i][j][q], s2, bb[q]), 0.f);
            *reinterpret_cast<f32x4*>(&C[(size_t)m * D_S + n]) = o;
            ushort4 hh;
            hh.x = f2bf(o[0]); hh.y = f2bf(o[1]);
            hh.z = f2bf(o[2]); hh.w = f2bf(o[3]);
            *reinterpret_cast<ushort4*>(&H[(size_t)m * D_S + n]) = hh;
        }
    }
}

// ---------------------------------------------------------------------------
// FALLBACK (round-5 verified): fused fp32 VALU transforms (ws too small).
// ---------------------------------------------------------------------------
#define NB0 ((B_C / 128) * (D_S / 128))     // 256
#define NB1 ((N_SRT / 128) * (D_S / 128))   // 512

__global__ __launch_bounds__(256)
void transform_fused(const float* __restrict__ A0, const float* __restrict__ W0,
                     const float* __restrict__ b0, float* __restrict__ C0,
                     unsigned short* __restrict__ H0,
                     const float* __restrict__ A1, const float* __restrict__ W1,
                     const float* __restrict__ b1, float* __restrict__ C1,
                     unsigned short* __restrict__ H1) {
    __shared__ __align__(16) float As[2][128][16];
    __shared__ __align__(16) float Bs[2][2048];

    const bool p1 = (int)blockIdx.x >= NB0;
    const int  b  = p1 ? (int)blockIdx.x - NB0 : (int)blockIdx.x;
    const float* __restrict__ A = p1 ? A1 : A0;
    const float* __restrict__ W = p1 ? W1 : W0;
    const float* __restrict__ bias = p1 ? b1 : b0;
    float* __restrict__ C = p1 ? C1 : C0;
    unsigned short* __restrict__ H = p1 ? H1 : H0;
    const int K = p1 ? D_S : D_C;

    const int bn = (b & 7) * 128;
    const int bm = (b >> 3) * 128;

    const int tid = threadIdx.x;
    const int tx = tid & 15, ty = tid >> 4;

    int a_off[2], w_off[2];
#pragma unroll
    for (int i = 0; i < 2; ++i) {
        const int idx = tid + i * 256;
        const int r = idx >> 2, q = idx & 3;
        a_off[i] = r * K + (q ^ ((r >> 3) & 3)) * 4;
        const int s = idx & 63;
        const int kloc = 2 * (idx >> 6) + ((s >> 4) & 1);
        const int cb   = 2 * (s & 15) + (s >> 5);
        w_off[i] = kloc * D_S + cb * 4;
    }

#define STAGE(bufi, k0)                                                        \
    {                                                                          \
        _Pragma("unroll")                                                      \
        for (int i = 0; i < 2; ++i) {                                          \
            const int idx = tid + i * 256;                                     \
            GLOAD_LDS16(A + (size_t)bm * K + (k0) + a_off[i],                  \
                        (char*)&As[bufi][0][0] + idx * 16);                    \
            GLOAD_LDS16(W + (size_t)(k0) * D_S + bn + w_off[i],                \
                        (char*)&Bs[bufi][0] + idx * 16);                       \
        }                                                                      \
    }

    float acc[8][8] = {};

    STAGE(0, 0);
    __syncthreads();

    const int nk = K / 16;
    for (int t = 0; t < nk; ++t) {
        const int cur = t & 1;
        if (t + 1 < nk) STAGE(t & 1 ? 0 : 1, (t + 1) * 16);

        const float* __restrict__ Bf = &Bs[cur][0];
#pragma unroll
        for (int kq = 0; kq < 4; ++kq) {
            f32x4 a4[8];
#pragma unroll
            for (int i = 0; i < 8; ++i)
                a4[i] = *reinterpret_cast<const f32x4*>(
                    &As[cur][ty * 8 + i][(kq ^ (ty & 3)) * 4]);
#pragma unroll
            for (int k2 = 0; k2 < 4; ++k2) {
                const int k = kq * 4 + k2;
                const int boff = (k >> 1) * 256 + (tx + ((k & 1) << 4)) * 4;
                const f32x4 bx = *reinterpret_cast<const f32x4*>(Bf + boff);
                const f32x4 by = *reinterpret_cast<const f32x4*>(Bf + boff + 128);
                const float bv[8] = {bx[0], bx[1], bx[2], bx[3], by[0], by[1], by[2], by[3]};
#pragma unroll
                for (int i = 0; i < 8; ++i) {
                    const float av = a4[i][k2];
#pragma unroll
                    for (int j = 0; j < 8; ++j)
                        acc[i][j] = fmaf(av, bv[j], acc[i][j]);
                }
            }
        }
        __syncthreads();
    }
#undef STAGE

    const f32x4 g0 = *reinterpret_cast<const f32x4*>(&bias[bn + tx * 8]);
    const f32x4 g1 = *reinterpret_cast<const f32x4*>(&bias[bn + tx * 8 + 4]);
#pragma unroll
    for (int i = 0; i < 8; ++i) {
        const int m = bm + ty * 8 + i;
        const int n = bn + tx * 8;
        f32x4 o0, o1;
#pragma unroll
        for (int j = 0; j < 4; ++j) {
            o0[j] = fmaxf(acc[i][j]     + g0[j], 0.f);
            o1[j] = fmaxf(acc[i][j + 4] + g1[j], 0.f);
        }
        *reinterpret_cast<f32x4*>(&C[(size_t)m * D_S + n])     = o0;
        *reinterpret_cast<f32x4*>(&C[(size_t)m * D_S + n + 4]) = o1;
        short8 h;
#pragma unroll
        for (int j = 0; j < 4; ++j) {
            h[j]     = (short)f2bf(o0[j]);
            h[j + 4] = (short)f2bf(o1[j]);
        }
        *reinterpret_cast<short8*>(&H[(size_t)m * D_S + n]) = h;
    }
}

// ---------------------------------------------------------------------------
// Kernel 2: bf16 MFMA score filter — round-15/16 verified. Unchanged.
// ---------------------------------------------------------------------------
__global__ __launch_bounds__(512)
void scores_filter(const unsigned short* __restrict__ TSh,
                   const unsigned short* __restrict__ TCh,
                   float* __restrict__ part) {     // [B_C][64] float4 entries
    __shared__ __align__(16) unsigned short sA[2][2][128 * 64];  // [parity][half]
    __shared__ __align__(16) unsigned short sB[2][2][128 * 64];
    const int tid  = threadIdx.x;
    const int lane = tid & 63;
    const int w    = tid >> 6;          // 0..7
    const int mw   = w >> 2;            // A(srt) half: 0..1
    const int nw   = w & 3;             // B(c) quarter: 0..3
    const int bh   = nw >> 1;           // B half this wave reads
    const int lr   = lane & 15, lg = lane >> 4;

    const int hw   = blockIdx.x;
    const int lgid = (hw & 7) * 64 + (hw >> 3);
    const int n0   = (lgid & 31) * 256;     // srt tile
    const int c0   = (lgid >> 5) * 256;     // comment tile

    const f32x4 vzero = {0.f, 0.f, 0.f, 0.f};
    f32x4 acc[8][4];
#pragma unroll
    for (int i = 0; i < 8; ++i)
#pragma unroll
        for (int j = 0; j < 4; ++j) acc[i][j] = vzero;

    auto stageHalf = [&](unsigned short* ldsbase, const unsigned short* grow0,
                         int kb) {
#pragma unroll
        for (int i = 0; i < 2; ++i) {
            const int idx = tid + i * 512;
            const int r   = idx >> 3;
            const int sw  = ((idx & 7) ^ (r & 7)) * 8;
            GLOAD_LDS16(grow0 + (size_t)r * D_S + kb + sw,
                        (char*)ldsbase + idx * 16);
        }
    };

    const unsigned short* TS0 = TSh + (size_t)n0 * D_S;
    const unsigned short* TS1 = TSh + (size_t)(n0 + 128) * D_S;
    const unsigned short* TC0 = TCh + (size_t)c0 * D_S;
    const unsigned short* TC1 = TCh + (size_t)(c0 + 128) * D_S;

    stageHalf(&sA[0][0][0], TS0, 0);
    stageHalf(&sA[0][1][0], TS1, 0);
    stageHalf(&sB[0][0][0], TC0, 0);
    stageHalf(&sB[0][1][0], TC1, 0);
    stageHalf(&sB[1][0][0], TC0, 64);
    stageHalf(&sB[1][1][0], TC1, 64);
    WAIT_VM4;
    __builtin_amdgcn_s_barrier();

    const int NITER = D_S / 128;        // 8 iterations, 2 K-steps each
    for (int t = 0; t < NITER; ++t) {
        const bool nl = (t + 1 < NITER);

#pragma unroll
        for (int par = 0; par < 2; ++par) {
            short8 bfr[4][2];
#pragma unroll
            for (int ph = 0; ph < 4; ++ph) {
                short8 afr[2][2];
                if (ph == 0) {
#pragma unroll
                    for (int j = 0; j < 4; ++j) {
                        const int rb = (nw & 1) * 64 + j * 16 + lr;
#pragma unroll
                        for (int kk = 0; kk < 2; ++kk)
                            bfr[j][kk] = *(const short8*)(
                                (const char*)&sB[par][bh][0] + rb * 128 +
                                (((kk * 4 + lg) ^ (rb & 7)) * 16));
                    }
                }
#pragma unroll
                for (int ii = 0; ii < 2; ++ii) {
                    const int ra = (ph * 2 + ii) * 16 + lr;
#pragma unroll
                    for (int kk = 0; kk < 2; ++kk)
                        afr[ii][kk] = *(const short8*)(
                            (const char*)&sA[par][mw][0] + ra * 128 +
                            (((kk * 4 + lg) ^ (ra & 7)) * 16));
                }
                if (par == 0) {
                    if (ph == 0)            stageHalf(&sA[1][0][0], TS0, (2*t+1)*64);
                    else if (ph == 1)       stageHalf(&sA[1][1][0], TS1, (2*t+1)*64);
                    else if (ph == 2) { if (nl) stageHalf(&sB[0][0][0], TC0, (2*t+2)*64); }
                    else              { if (nl) stageHalf(&sB[0][1][0], TC1, (2*t+2)*64); }
                } else {
                    if (ph == 0)      { if (nl) stageHalf(&sA[0][0][0], TS0, (2*t+2)*64); }
                    else if (ph == 1) { if (nl) stageHalf(&sA[0][1][0], TS1, (2*t+2)*64); }
                    else if (ph == 2) { if (nl) stageHalf(&sB[1][0][0], TC0, (2*t+3)*64); }
                    else              { if (nl) stageHalf(&sB[1][1][0], TC1, (2*t+3)*64); }
                }
                if (ph == 3) { if (nl) { WAIT_VM4; } else { WAIT_VM0; } }
                __builtin_amdgcn_s_barrier();
                WAIT_LGKM;
                __builtin_amdgcn_s_setprio(1);
#pragma unroll
                for (int ii = 0; ii < 2; ++ii)
#pragma unroll
                    for (int j = 0; j < 4; ++j)
#pragma unroll
                        for (int kk = 0; kk < 2; ++kk)
                            acc[ph * 2 + ii][j] = __builtin_amdgcn_mfma_f32_16x16x32_bf16(
                                afr[ii][kk], bfr[j][kk], acc[ph * 2 + ii][j], 0, 0, 0);
                __builtin_amdgcn_s_setprio(0);
                __builtin_amdgcn_s_barrier();
            }
        }
    }

    // epilogue: per-(c, half) top-2 -> part (round-16 verified)
    const int gbase = (n0 >> 2) + mw * 32;
#pragma unroll
    for (int j = 0; j < 4; ++j) {
        float v1 = -INFINITY, v2 = -INFINITY;
        int   g1 = 0, g2 = 0;
#pragma unroll
        for (int i = 0; i < 8; ++i) {
            const f32x4 v = acc[i][j];
            const float m = fmaxf(fmaxf(v.x, v.y), fmaxf(v.z, v.w));
            const int g = gbase + i * 4 + lg;
            if (m > v1)      { v2 = v1; g2 = g1; v1 = m; g1 = g; }
            else if (m > v2) { v2 = m; g2 = g; }
        }
#pragma unroll
        for (int off = 16; off <= 32; off <<= 1) {
            const float ov1 = __shfl_xor(v1, off);
            const int   og1 = __shfl_xor(g1, off);
            const float ov2 = __shfl_xor(v2, off);
            const int   og2 = __shfl_xor(g2, off);
            if (ov1 > v1 || (ov1 == v1 && og1 < g1)) { v2 = v1; g2 = g1; v1 = ov1; g1 = og1; }
            else if (ov1 > v2 || (ov1 == v2 && og1 < g2)) { v2 = ov1; g2 = og1; }
            if (ov2 > v1 || (ov2 == v1 && og2 < g1)) { v2 = v1; g2 = g1; v1 = ov2; g1 = og2; }
            else if (ov2 > v2 || (ov2 == v2 && og2 < g2)) { v2 = ov2; g2 = og2; }
        }
        if (lg == 0) {
            const int c = c0 + nw * 64 + j * 16 + lr;
            const int blk2 = (lgid & 31) * 2 + mw;
            f32x4 e;
            e[0] = v1; e[1] = __int_as_float(g1);
            e[2] = v2; e[3] = __int_as_float(g2);
            *reinterpret_cast<f32x4*>(&part[((size_t)c * 64 + blk2) * 4]) = e;
        }
    }
}

// ---------------------------------------------------------------------------
// Kernel 3: fused merge + refine + gather (round-17 verified). Unchanged.
// ---------------------------------------------------------------------------
__global__ __launch_bounds__(256)
void refine_gather(const float* __restrict__ t_c, const float* __restrict__ t_s,
                   const float* __restrict__ part, float* __restrict__ out) {
    __shared__ float tc[D_S];
    __shared__ float sc[4 * PGRP];
    __shared__ int   selg[PGRP];
    __shared__ int   sel[2];
    const int row = blockIdx.x;
    const int tid = threadIdx.x;
    *reinterpret_cast<float4*>(&tc[tid * 4]) =
        *reinterpret_cast<const float4*>(&t_c[(size_t)row * D_S + tid * 4]);
    const int w = tid >> 6, lane = tid & 63;

    if (w == 0) {   // merge: lane holds one part entry (2 candidates)
        const f32x4 e = *reinterpret_cast<const f32x4*>(
            &part[((size_t)row * 64 + lane) * 4]);
        const float v[2]  = {e[0], e[2]};
        const int   gi[2] = {__float_as_int(e[1]), __float_as_int(e[3])};
        float pv = INFINITY; int pi = -1;
        int gl[PGRP];
#pragma unroll
        for (int k = 0; k < PGRP; ++k) {
            float bv = -INFINITY; int bi = 0x7FFFFFFF;
#pragma unroll
            for (int s = 0; s < 2; ++s) {
                const bool after  = (v[s] < pv) || (v[s] == pv && gi[s] > pi);
                const bool before = (v[s] > bv) || (v[s] == bv && gi[s] < bi);
                if (after && before) { bv = v[s]; bi = gi[s]; }
            }
#pragma unroll
            for (int off = 32; off >= 1; off >>= 1) {
                const float ov = __shfl_xor(bv, off);
                const int   oi = __shfl_xor(bi, off);
                if ((ov > bv) || (ov == bv && oi < bi)) { bv = ov; bi = oi; }
            }
            gl[k] = bi; pv = bv; pi = bi;
        }
#pragma unroll
        for (int a = 0; a < PGRP; ++a)
#pragma unroll
            for (int b2 = 0; b2 < PGRP - 1; ++b2)
                if (gl[b2] > gl[b2 + 1]) { int t = gl[b2]; gl[b2] = gl[b2 + 1]; gl[b2 + 1] = t; }
        if (lane == 0) {
#pragma unroll
            for (int k = 0; k < PGRP; ++k) selg[k] = gl[k];
        }
    }
    __syncthreads();

    float4 c4[4];
#pragma unroll
    for (int q = 0; q < 4; ++q)
        c4[q] = *reinterpret_cast<const float4*>(&tc[lane * 16 + q * 4]);
    const int g = selg[w];               // one group per wave
#pragma unroll
    for (int o = 0; o < 4; ++o) {
        const int n = g * 4 + o;
        const float* ts = t_s + (size_t)n * D_S + lane * 16;
        float p = 0.f;
#pragma unroll
        for (int q = 0; q < 4; ++q) {
            const float4 tv = *reinterpret_cast<const float4*>(ts + q * 4);
            p += c4[q].x * tv.x + c4[q].y * tv.y + c4[q].z * tv.z + c4[q].w * tv.w;
        }
#pragma unroll
        for (int off = 32; off >= 1; off >>= 1) p += __shfl_xor(p, off);
        if (lane == 0) sc[w * 4 + o] = p;
    }
    __syncthreads();
    if (tid == 0) {
        float v1 = -INFINITY, v2 = -INFINITY; int i1 = 0, i2 = 0;
#pragma unroll
        for (int s = 0; s < 4 * PGRP; ++s) {   // selg sorted => ascending n
            const int n = selg[s >> 2] * 4 + (s & 3);
            const float v = sc[s];
            if (v > v1)      { v2 = v1; i2 = i1; v1 = v; i1 = n; }
            else if (v > v2) { v2 = v; i2 = n; }
        }
        sel[0] = i1; sel[1] = i2;
    }
    __syncthreads();
#pragma unroll
    for (int q = 0; q < 2; ++q) {
        const int src = sel[q];
        const float4 v = *reinterpret_cast<const float4*>(
            &t_s[(size_t)src * D_S + tid * 4]);
        *reinterpret_cast<float4*>(
            &out[((size_t)row * KSEL + q) * D_S + tid * 4]) = v;
    }
}

// ---------------------------------------------------------------------------
extern "C" void kernel_launch(void* const* d_in, const int* in_sizes, int n_in,
                              void* d_out, int out_size, void* d_ws, size_t ws_size,
                              hipStream_t stream) {
    const float* srt      = (const float*)d_in[0];  // [8192,1024]
    const float* comments = (const float*)d_in[1];  // [4096,768]
    const float* Wc       = (const float*)d_in[2];  // [768,1024]
    const float* bc       = (const float*)d_in[3];  // [1024]
    const float* Ws       = (const float*)d_in[4];  // [1024,1024]
    const float* bs       = (const float*)d_in[5];  // [1024]
    float* out = (float*)d_out;

    // base workspace layout
    char* p = (char*)d_ws;
    float* t_c = (float*)p;          p += (size_t)B_C * D_S * 4;     // 16 MB
    float* t_s = (float*)p;          p += (size_t)N_SRT * D_S * 4;   // 32 MB
    unsigned short* tc_h = (unsigned short*)p; p += (size_t)B_C * D_S * 2;    // 8 MB
    unsigned short* ts_h = (unsigned short*)p; p += (size_t)N_SRT * D_S * 2;  // 16 MB
    float* part = (float*)p;         p += (size_t)B_C * NGRP * 2;    // part in G's old slot
    p += (size_t)B_C * PGRP * 4;
    p += (size_t)B_C * KSEL * 4;

    // fp16 2-plane workspace (appended; ~53.4 MB)
    _Float16* actS = (_Float16*)p; p += 2 * (size_t)N_SRT * D_S * 2; // 33.5 MB
    _Float16* actC = (_Float16*)p; p += 2 * (size_t)B_C * D_C * 2;   // 12.6 MB
    _Float16* wtS  = (_Float16*)p; p += 2 * (size_t)D_S * D_S * 2;   // 4.2 MB
    _Float16* wtC  = (_Float16*)p; p += 2 * (size_t)D_S * D_C * 2;   // 3.1 MB
    const size_t required = (size_t)(p - (char*)d_ws);

    if (ws_size >= required) {
        // --- scaled fp16x3 MFMA transform path (8-phase template) ---
        split_all<<<NS_ACT + 448, 256, 0, stream>>>(
            srt, comments, actS, actC, Ws, wtS, Wc, wtC);

        transform_8ph<<<256 + 128, 512, 0, stream>>>(
            actS, wtS, bs, t_s, ts_h,
            actC, wtC, bc, t_c, tc_h);
    } else {
        // --- fallback: round-5 verified fp32 VALU path ---
        transform_fused<<<NB0 + NB1, 256, 0, stream>>>(
            comments, Wc, bc, t_c, tc_h,
            srt,      Ws, bs, t_s, ts_h);
    }

    scores_filter<<<512, 512, 0, stream>>>(ts_h, tc_h, part);
    refine_gather<<<B_C, 256, 0, stream>>>(t_c, t_s, part, out);
}

// Round 19
// 217.073 us; speedup vs baseline: 1.1117x; 1.1117x over previous
//
#include <hip/hip_runtime.h>
#include <math.h>

#define B_C   4096   // comments
#define N_SRT 8192   // srt rows
#define D_C   768
#define D_S   1024
#define KSEL  2
#define NGRP  (N_SRT / 4)   // 2048 groups of 4 consecutive srt rows
#define PGRP  4             // groups refined per comment row (16 candidates)

typedef float    f32x4  __attribute__((ext_vector_type(4)));
typedef short    short8 __attribute__((ext_vector_type(8)));
typedef _Float16 half8  __attribute__((ext_vector_type(8)));

__device__ inline unsigned short f2bf(float f) {           // RTNE float->bf16
    unsigned u = __float_as_uint(f);
    u += 0x7FFF + ((u >> 16) & 1);
    return (unsigned short)(u >> 16);
}
__device__ inline float bf2f(unsigned short h) {
    return __uint_as_float(((unsigned)h) << 16);
}

#define GLOAD_LDS16(gsrc, ldst)                                                     \
    __builtin_amdgcn_global_load_lds(                                               \
        (const __attribute__((address_space(1))) void*)(gsrc),                      \
        (__attribute__((address_space(3))) void*)(ldst), 16, 0, 0)

// counted-vmcnt barrier pieces
#define WAIT_VM4  asm volatile("s_waitcnt vmcnt(4)" ::: "memory")
#define WAIT_VM0  asm volatile("s_waitcnt vmcnt(0)" ::: "memory")
#define WAIT_LGKM asm volatile("s_waitcnt lgkmcnt(0)" ::: "memory")

// ---------------------------------------------------------------------------
// split_all: act split + weight split in ONE launch (round-16 verified).
// ---------------------------------------------------------------------------
#define NS_ACT ((N_SRT * D_S / 8 + B_C * D_C / 8) / 256)   // 5632

__global__ __launch_bounds__(256)
void split_all(const float* __restrict__ srt, const float* __restrict__ com,
               _Float16* __restrict__ pS, _Float16* __restrict__ pC,
               const float* __restrict__ Ws, _Float16* __restrict__ WtS,
               const float* __restrict__ Wc, _Float16* __restrict__ WtC) {
    __shared__ float t[64][65];
    if ((int)blockIdx.x < NS_ACT) {
        const int g = blockIdx.x * 256 + threadIdx.x;
        const int E0 = N_SRT * D_S / 8;
        const float* src;
        _Float16* dst;
        size_t stride;
        if (g < E0) {
            src = srt + (size_t)g * 8; dst = pS + (size_t)g * 8;
            stride = (size_t)N_SRT * D_S;
        } else {
            const int g2 = g - E0;
            src = com + (size_t)g2 * 8; dst = pC + (size_t)g2 * 8;
            stride = (size_t)B_C * D_C;
        }
        const float4 a = *reinterpret_cast<const float4*>(src);
        const float4 b = *reinterpret_cast<const float4*>(src + 4);
        const float x[8] = {a.x, a.y, a.z, a.w, b.x, b.y, b.z, b.w};
        half8 hv, mv;
#pragma unroll
        for (int j = 0; j < 8; ++j) {
            const _Float16 h = (_Float16)x[j];
            const float    r = x[j] - (float)h;          // exact
            hv[j] = h; mv[j] = (_Float16)(r * 2048.0f);
        }
        *reinterpret_cast<half8*>(dst)          = hv;
        *reinterpret_cast<half8*>(dst + stride) = mv;
    } else {
        const int bb = (int)blockIdx.x - NS_ACT;
        const bool p1 = bb >= 256;
        const int  b  = p1 ? bb - 256 : bb;
        const float* __restrict__ W = p1 ? Wc : Ws;
        _Float16* __restrict__ Wt   = p1 ? WtC : WtS;
        const int K  = p1 ? D_C : D_S;
        const int n0 = (b & 15) * 64, k0 = (b >> 4) * 64;

        const int tid = threadIdx.x;
        const int c = tid & 63, rq = tid >> 6;
#pragma unroll
        for (int j = 0; j < 16; ++j) {
            const int kr = rq * 16 + j;
            t[kr][c] = W[(size_t)(k0 + kr) * D_S + n0 + c];
        }
        __syncthreads();
        const size_t PS = (size_t)K * D_S;
#pragma unroll
        for (int j = 0; j < 16; ++j) {
            const int nr = rq * 16 + j;
            const float xs = t[c][nr] * 32768.0f;        // exact (pow2 scale)
            const _Float16 h = (_Float16)xs;
            const float    r = xs - (float)h;            // exact
            const size_t o = (size_t)(n0 + nr) * K + k0 + c;
            Wt[o]      = h;
            Wt[o + PS] = (_Float16)(r * 2048.0f);
        }
    }
}

// ---------------------------------------------------------------------------
// transform_mfma_all: round-13 verified (chunk-fused scaled fp16x3).
// RESTORED after round-18's 8-phase port regressed (8 MFMA/barrier + 384-
// block tail vs this kernel's 48 MFMA/barrier at 2 blocks/CU).
// ---------------------------------------------------------------------------
__global__ __launch_bounds__(256)
void transform_mfma_all(const _Float16* __restrict__ actS,
                        const _Float16* __restrict__ wtS,
                        const float* __restrict__ bS,
                        float* __restrict__ CS, unsigned short* __restrict__ HS,
                        const _Float16* __restrict__ actC,
                        const _Float16* __restrict__ wtC,
                        const float* __restrict__ bC,
                        float* __restrict__ CC, unsigned short* __restrict__ HC) {
    __shared__ __align__(16) _Float16 sW[2][2][128 * 32];  // [buf][plane]
    __shared__ __align__(16) _Float16 sA[2][2][128 * 32];
    const int tid  = threadIdx.x;
    const int lane = tid & 63;
    const int w    = tid >> 6;
    const int lr   = lane & 15, lg = lane >> 4;
    const int wn   = w & 1, wc = w >> 1;

    const int hw = blockIdx.x;
    int lgid, seg;
    if (hw < 512) { seg = 0; lgid = (hw & 7) * 64 + (hw >> 3); }
    else          { const int h2 = hw - 512; seg = 1; lgid = (h2 & 7) * 32 + (h2 >> 3); }

    const _Float16* __restrict__ actP = seg ? actC : actS;
    const _Float16* __restrict__ wtP  = seg ? wtC  : wtS;
    const float* __restrict__ bias    = seg ? bC   : bS;
    float* __restrict__ C             = seg ? CC   : CS;
    unsigned short* __restrict__ H    = seg ? HC   : HS;
    const int K   = seg ? D_C : D_S;
    const int NC  = seg ? (D_C / 32) : (D_S / 32);    // 24 : 32 chunks
    const size_t aps = seg ? (size_t)B_C * D_C : (size_t)N_SRT * D_S;
    const size_t wps = (size_t)D_S * K;

    const int bn = (lgid & 7) * 128;
    const int bm = (lgid >> 3) * 128;

    const f32x4 vzero = {0.f, 0.f, 0.f, 0.f};
    f32x4 acc[4][4];
#pragma unroll
    for (int i = 0; i < 4; ++i)
#pragma unroll
        for (int j = 0; j < 4; ++j) acc[i][j] = vzero;

    auto stage = [&](int buf, int c) {
        const int kb = c * 32;
#pragma unroll
        for (int i = 0; i < 2; ++i) {
            const int idx = tid + i * 256;
            const int r   = idx >> 2;
            const int sw  = ((idx & 3) ^ ((r >> 1) & 3)) * 8;
            const size_t wo = (size_t)(bn + r) * K + kb + sw;
            const size_t ao = (size_t)(bm + r) * K + kb + sw;
            GLOAD_LDS16(wtP  + wo,       (char*)&sW[buf][0][0] + idx * 16);
            GLOAD_LDS16(wtP  + wps + wo, (char*)&sW[buf][1][0] + idx * 16);
            GLOAD_LDS16(actP + ao,       (char*)&sA[buf][0][0] + idx * 16);
            GLOAD_LDS16(actP + aps + ao, (char*)&sA[buf][1][0] + idx * 16);
        }
    };

    stage(0, 0);
    WAIT_VM0;
    __builtin_amdgcn_s_barrier();

    for (int c = 0; c < NC; ++c) {
        const int cur = c & 1;
        if (c + 1 < NC) stage(cur ^ 1, c + 1);

        half8 a0[4], a1[4], b0[4], b1[4], b0s[4];
#pragma unroll
        for (int t4 = 0; t4 < 4; ++t4) {
            const int ra = wn * 64 + t4 * 16 + lr;
            const int oa = ra * 64 + ((lg ^ ((ra >> 1) & 3)) * 16);
            a0[t4] = *(const half8*)((const char*)&sW[cur][0][0] + oa);
            a1[t4] = *(const half8*)((const char*)&sW[cur][1][0] + oa);
            const int rb = wc * 64 + t4 * 16 + lr;
            const int ob = rb * 64 + ((lg ^ ((rb >> 1) & 3)) * 16);
            b0[t4] = *(const half8*)((const char*)&sA[cur][0][0] + ob);
            b1[t4] = *(const half8*)((const char*)&sA[cur][1][0] + ob);
            b0s[t4] = b0[t4] * (_Float16)2048.0f;    // exact pow2
        }
        __builtin_amdgcn_s_setprio(1);
#pragma unroll
        for (int i = 0; i < 4; ++i)
#pragma unroll
            for (int j = 0; j < 4; ++j) {
                acc[i][j] = __builtin_amdgcn_mfma_f32_16x16x32_f16(
                    a0[i], b0s[j], acc[i][j], 0, 0, 0);   // hh (2^26)
                acc[i][j] = __builtin_amdgcn_mfma_f32_16x16x32_f16(
                    a0[i], b1[j],  acc[i][j], 0, 0, 0);   // hm (2^26)
                acc[i][j] = __builtin_amdgcn_mfma_f32_16x16x32_f16(
                    a1[i], b0[j],  acc[i][j], 0, 0, 0);   // mh (2^26)
            }
        __builtin_amdgcn_s_setprio(0);

        WAIT_VM0;
        WAIT_LGKM;
        __builtin_amdgcn_s_barrier();
    }

    const float s2 = 1.4901161193847656e-8f;    // 2^-26
#pragma unroll
    for (int i = 0; i < 4; ++i) {
        const int n = bn + wn * 64 + i * 16 + lg * 4;
        const f32x4 bb = *reinterpret_cast<const f32x4*>(&bias[n]);
#pragma unroll
        for (int j = 0; j < 4; ++j) {
            const int m = bm + wc * 64 + j * 16 + lr;
            f32x4 o;
#pragma unroll
            for (int q = 0; q < 4; ++q)
                o[q] = fmaxf(fmaf(acc[i][j][q], s2, bb[q]), 0.f);
            *reinterpret_cast<f32x4*>(&C[(size_t)m * D_S + n]) = o;
            ushort4 hh;
            hh.x = f2bf(o[0]); hh.y = f2bf(o[1]);
            hh.z = f2bf(o[2]); hh.w = f2bf(o[3]);
            *reinterpret_cast<ushort4*>(&H[(size_t)m * D_S + n]) = hh;
        }
    }
}

// ---------------------------------------------------------------------------
// FALLBACK (round-5 verified): fused fp32 VALU transforms (ws too small).
// ---------------------------------------------------------------------------
#define NB0 ((B_C / 128) * (D_S / 128))     // 256
#define NB1 ((N_SRT / 128) * (D_S / 128))   // 512

__global__ __launch_bounds__(256)
void transform_fused(const float* __restrict__ A0, const float* __restrict__ W0,
                     const float* __restrict__ b0, float* __restrict__ C0,
                     unsigned short* __restrict__ H0,
                     const float* __restrict__ A1, const float* __restrict__ W1,
                     const float* __restrict__ b1, float* __restrict__ C1,
                     unsigned short* __restrict__ H1) {
    __shared__ __align__(16) float As[2][128][16];
    __shared__ __align__(16) float Bs[2][2048];

    const bool p1 = (int)blockIdx.x >= NB0;
    const int  b  = p1 ? (int)blockIdx.x - NB0 : (int)blockIdx.x;
    const float* __restrict__ A = p1 ? A1 : A0;
    const float* __restrict__ W = p1 ? W1 : W0;
    const float* __restrict__ bias = p1 ? b1 : b0;
    float* __restrict__ C = p1 ? C1 : C0;
    unsigned short* __restrict__ H = p1 ? H1 : H0;
    const int K = p1 ? D_S : D_C;

    const int bn = (b & 7) * 128;
    const int bm = (b >> 3) * 128;

    const int tid = threadIdx.x;
    const int tx = tid & 15, ty = tid >> 4;

    int a_off[2], w_off[2];
#pragma unroll
    for (int i = 0; i < 2; ++i) {
        const int idx = tid + i * 256;
        const int r = idx >> 2, q = idx & 3;
        a_off[i] = r * K + (q ^ ((r >> 3) & 3)) * 4;
        const int s = idx & 63;
        const int kloc = 2 * (idx >> 6) + ((s >> 4) & 1);
        const int cb   = 2 * (s & 15) + (s >> 5);
        w_off[i] = kloc * D_S + cb * 4;
    }

#define STAGE(bufi, k0)                                                        \
    {                                                                          \
        _Pragma("unroll")                                                      \
        for (int i = 0; i < 2; ++i) {                                          \
            const int idx = tid + i * 256;                                     \
            GLOAD_LDS16(A + (size_t)bm * K + (k0) + a_off[i],                  \
                        (char*)&As[bufi][0][0] + idx * 16);                    \
            GLOAD_LDS16(W + (size_t)(k0) * D_S + bn + w_off[i],                \
                        (char*)&Bs[bufi][0] + idx * 16);                       \
        }                                                                      \
    }

    float acc[8][8] = {};

    STAGE(0, 0);
    __syncthreads();

    const int nk = K / 16;
    for (int t = 0; t < nk; ++t) {
        const int cur = t & 1;
        if (t + 1 < nk) STAGE(t & 1 ? 0 : 1, (t + 1) * 16);

        const float* __restrict__ Bf = &Bs[cur][0];
#pragma unroll
        for (int kq = 0; kq < 4; ++kq) {
            f32x4 a4[8];
#pragma unroll
            for (int i = 0; i < 8; ++i)
                a4[i] = *reinterpret_cast<const f32x4*>(
                    &As[cur][ty * 8 + i][(kq ^ (ty & 3)) * 4]);
#pragma unroll
            for (int k2 = 0; k2 < 4; ++k2) {
                const int k = kq * 4 + k2;
                const int boff = (k >> 1) * 256 + (tx + ((k & 1) << 4)) * 4;
                const f32x4 bx = *reinterpret_cast<const f32x4*>(Bf + boff);
                const f32x4 by = *reinterpret_cast<const f32x4*>(Bf + boff + 128);
                const float bv[8] = {bx[0], bx[1], bx[2], bx[3], by[0], by[1], by[2], by[3]};
#pragma unroll
                for (int i = 0; i < 8; ++i) {
                    const float av = a4[i][k2];
#pragma unroll
                    for (int j = 0; j < 8; ++j)
                        acc[i][j] = fmaf(av, bv[j], acc[i][j]);
                }
            }
        }
        __syncthreads();
    }
#undef STAGE

    const f32x4 g0 = *reinterpret_cast<const f32x4*>(&bias[bn + tx * 8]);
    const f32x4 g1 = *reinterpret_cast<const f32x4*>(&bias[bn + tx * 8 + 4]);
#pragma unroll
    for (int i = 0; i < 8; ++i) {
        const int m = bm + ty * 8 + i;
        const int n = bn + tx * 8;
        f32x4 o0, o1;
#pragma unroll
        for (int j = 0; j < 4; ++j) {
            o0[j] = fmaxf(acc[i][j]     + g0[j], 0.f);
            o1[j] = fmaxf(acc[i][j + 4] + g1[j], 0.f);
        }
        *reinterpret_cast<f32x4*>(&C[(size_t)m * D_S + n])     = o0;
        *reinterpret_cast<f32x4*>(&C[(size_t)m * D_S + n + 4]) = o1;
        short8 h;
#pragma unroll
        for (int j = 0; j < 4; ++j) {
            h[j]     = (short)f2bf(o0[j]);
            h[j + 4] = (short)f2bf(o1[j]);
        }
        *reinterpret_cast<short8*>(&H[(size_t)m * D_S + n]) = h;
    }
}

// ---------------------------------------------------------------------------
// Kernel 2: bf16 MFMA score filter — round-15/16 verified. Unchanged.
// ---------------------------------------------------------------------------
__global__ __launch_bounds__(512)
void scores_filter(const unsigned short* __restrict__ TSh,
                   const unsigned short* __restrict__ TCh,
                   float* __restrict__ part) {     // [B_C][64] float4 entries
    __shared__ __align__(16) unsigned short sA[2][2][128 * 64];  // [parity][half]
    __shared__ __align__(16) unsigned short sB[2][2][128 * 64];
    const int tid  = threadIdx.x;
    const int lane = tid & 63;
    const int w    = tid >> 6;          // 0..7
    const int mw   = w >> 2;            // A(srt) half: 0..1
    const int nw   = w & 3;             // B(c) quarter: 0..3
    const int bh   = nw >> 1;           // B half this wave reads
    const int lr   = lane & 15, lg = lane >> 4;

    const int hw   = blockIdx.x;
    const int lgid = (hw & 7) * 64 + (hw >> 3);
    const int n0   = (lgid & 31) * 256;     // srt tile
    const int c0   = (lgid >> 5) * 256;     // comment tile

    const f32x4 vzero = {0.f, 0.f, 0.f, 0.f};
    f32x4 acc[8][4];
#pragma unroll
    for (int i = 0; i < 8; ++i)
#pragma unroll
        for (int j = 0; j < 4; ++j) acc[i][j] = vzero;

    auto stageHalf = [&](unsigned short* ldsbase, const unsigned short* grow0,
                         int kb) {
#pragma unroll
        for (int i = 0; i < 2; ++i) {
            const int idx = tid + i * 512;
            const int r   = idx >> 3;
            const int sw  = ((idx & 7) ^ (r & 7)) * 8;
            GLOAD_LDS16(grow0 + (size_t)r * D_S + kb + sw,
                        (char*)ldsbase + idx * 16);
        }
    };

    const unsigned short* TS0 = TSh + (size_t)n0 * D_S;
    const unsigned short* TS1 = TSh + (size_t)(n0 + 128) * D_S;
    const unsigned short* TC0 = TCh + (size_t)c0 * D_S;
    const unsigned short* TC1 = TCh + (size_t)(c0 + 128) * D_S;

    stageHalf(&sA[0][0][0], TS0, 0);
    stageHalf(&sA[0][1][0], TS1, 0);
    stageHalf(&sB[0][0][0], TC0, 0);
    stageHalf(&sB[0][1][0], TC1, 0);
    stageHalf(&sB[1][0][0], TC0, 64);
    stageHalf(&sB[1][1][0], TC1, 64);
    WAIT_VM4;
    __builtin_amdgcn_s_barrier();

    const int NITER = D_S / 128;        // 8 iterations, 2 K-steps each
    for (int t = 0; t < NITER; ++t) {
        const bool nl = (t + 1 < NITER);

#pragma unroll
        for (int par = 0; par < 2; ++par) {
            short8 bfr[4][2];
#pragma unroll
            for (int ph = 0; ph < 4; ++ph) {
                short8 afr[2][2];
                if (ph == 0) {
#pragma unroll
                    for (int j = 0; j < 4; ++j) {
                        const int rb = (nw & 1) * 64 + j * 16 + lr;
#pragma unroll
                        for (int kk = 0; kk < 2; ++kk)
                            bfr[j][kk] = *(const short8*)(
                                (const char*)&sB[par][bh][0] + rb * 128 +
                                (((kk * 4 + lg) ^ (rb & 7)) * 16));
                    }
                }
#pragma unroll
                for (int ii = 0; ii < 2; ++ii) {
                    const int ra = (ph * 2 + ii) * 16 + lr;
#pragma unroll
                    for (int kk = 0; kk < 2; ++kk)
                        afr[ii][kk] = *(const short8*)(
                            (const char*)&sA[par][mw][0] + ra * 128 +
                            (((kk * 4 + lg) ^ (ra & 7)) * 16));
                }
                if (par == 0) {
                    if (ph == 0)            stageHalf(&sA[1][0][0], TS0, (2*t+1)*64);
                    else if (ph == 1)       stageHalf(&sA[1][1][0], TS1, (2*t+1)*64);
                    else if (ph == 2) { if (nl) stageHalf(&sB[0][0][0], TC0, (2*t+2)*64); }
                    else              { if (nl) stageHalf(&sB[0][1][0], TC1, (2*t+2)*64); }
                } else {
                    if (ph == 0)      { if (nl) stageHalf(&sA[0][0][0], TS0, (2*t+2)*64); }
                    else if (ph == 1) { if (nl) stageHalf(&sA[0][1][0], TS1, (2*t+2)*64); }
                    else if (ph == 2) { if (nl) stageHalf(&sB[1][0][0], TC0, (2*t+3)*64); }
                    else              { if (nl) stageHalf(&sB[1][1][0], TC1, (2*t+3)*64); }
                }
                if (ph == 3) { if (nl) { WAIT_VM4; } else { WAIT_VM0; } }
                __builtin_amdgcn_s_barrier();
                WAIT_LGKM;
                __builtin_amdgcn_s_setprio(1);
#pragma unroll
                for (int ii = 0; ii < 2; ++ii)
#pragma unroll
                    for (int j = 0; j < 4; ++j)
#pragma unroll
                        for (int kk = 0; kk < 2; ++kk)
                            acc[ph * 2 + ii][j] = __builtin_amdgcn_mfma_f32_16x16x32_bf16(
                                afr[ii][kk], bfr[j][kk], acc[ph * 2 + ii][j], 0, 0, 0);
                __builtin_amdgcn_s_setprio(0);
                __builtin_amdgcn_s_barrier();
            }
        }
    }

    // epilogue: per-(c, half) top-2 -> part (round-16 verified)
    const int gbase = (n0 >> 2) + mw * 32;
#pragma unroll
    for (int j = 0; j < 4; ++j) {
        float v1 = -INFINITY, v2 = -INFINITY;
        int   g1 = 0, g2 = 0;
#pragma unroll
        for (int i = 0; i < 8; ++i) {
            const f32x4 v = acc[i][j];
            const float m = fmaxf(fmaxf(v.x, v.y), fmaxf(v.z, v.w));
            const int g = gbase + i * 4 + lg;
            if (m > v1)      { v2 = v1; g2 = g1; v1 = m; g1 = g; }
            else if (m > v2) { v2 = m; g2 = g; }
        }
#pragma unroll
        for (int off = 16; off <= 32; off <<= 1) {
            const float ov1 = __shfl_xor(v1, off);
            const int   og1 = __shfl_xor(g1, off);
            const float ov2 = __shfl_xor(v2, off);
            const int   og2 = __shfl_xor(g2, off);
            if (ov1 > v1 || (ov1 == v1 && og1 < g1)) { v2 = v1; g2 = g1; v1 = ov1; g1 = og1; }
            else if (ov1 > v2 || (ov1 == v2 && og1 < g2)) { v2 = ov1; g2 = og1; }
            if (ov2 > v1 || (ov2 == v1 && og2 < g1)) { v2 = v1; g2 = g1; v1 = ov2; g1 = og2; }
            else if (ov2 > v2 || (ov2 == v2 && og2 < g2)) { v2 = ov2; g2 = og2; }
        }
        if (lg == 0) {
            const int c = c0 + nw * 64 + j * 16 + lr;
            const int blk2 = (lgid & 31) * 2 + mw;
            f32x4 e;
            e[0] = v1; e[1] = __int_as_float(g1);
            e[2] = v2; e[3] = __int_as_float(g2);
            *reinterpret_cast<f32x4*>(&part[((size_t)c * 64 + blk2) * 4]) = e;
        }
    }
}

// ---------------------------------------------------------------------------
// Kernel 3: fused merge + refine + gather (round-17 verified). Unchanged.
// ---------------------------------------------------------------------------
__global__ __launch_bounds__(256)
void refine_gather(const float* __restrict__ t_c, const float* __restrict__ t_s,
                   const float* __restrict__ part, float* __restrict__ out) {
    __shared__ float tc[D_S];
    __shared__ float sc[4 * PGRP];
    __shared__ int   selg[PGRP];
    __shared__ int   sel[2];
    const int row = blockIdx.x;
    const int tid = threadIdx.x;
    *reinterpret_cast<float4*>(&tc[tid * 4]) =
        *reinterpret_cast<const float4*>(&t_c[(size_t)row * D_S + tid * 4]);
    const int w = tid >> 6, lane = tid & 63;

    if (w == 0) {   // merge: lane holds one part entry (2 candidates)
        const f32x4 e = *reinterpret_cast<const f32x4*>(
            &part[((size_t)row * 64 + lane) * 4]);
        const float v[2]  = {e[0], e[2]};
        const int   gi[2] = {__float_as_int(e[1]), __float_as_int(e[3])};
        float pv = INFINITY; int pi = -1;
        int gl[PGRP];
#pragma unroll
        for (int k = 0; k < PGRP; ++k) {
            float bv = -INFINITY; int bi = 0x7FFFFFFF;
#pragma unroll
            for (int s = 0; s < 2; ++s) {
                const bool after  = (v[s] < pv) || (v[s] == pv && gi[s] > pi);
                const bool before = (v[s] > bv) || (v[s] == bv && gi[s] < bi);
                if (after && before) { bv = v[s]; bi = gi[s]; }
            }
#pragma unroll
            for (int off = 32; off >= 1; off >>= 1) {
                const float ov = __shfl_xor(bv, off);
                const int   oi = __shfl_xor(bi, off);
                if ((ov > bv) || (ov == bv && oi < bi)) { bv = ov; bi = oi; }
            }
            gl[k] = bi; pv = bv; pi = bi;
        }
#pragma unroll
        for (int a = 0; a < PGRP; ++a)
#pragma unroll
            for (int b2 = 0; b2 < PGRP - 1; ++b2)
                if (gl[b2] > gl[b2 + 1]) { int t = gl[b2]; gl[b2] = gl[b2 + 1]; gl[b2 + 1] = t; }
        if (lane == 0) {
#pragma unroll
            for (int k = 0; k < PGRP; ++k) selg[k] = gl[k];
        }
    }
    __syncthreads();

    float4 c4[4];
#pragma unroll
    for (int q = 0; q < 4; ++q)
        c4[q] = *reinterpret_cast<const float4*>(&tc[lane * 16 + q * 4]);
    const int g = selg[w];               // one group per wave
#pragma unroll
    for (int o = 0; o < 4; ++o) {
        const int n = g * 4 + o;
        const float* ts = t_s + (size_t)n * D_S + lane * 16;
        float p = 0.f;
#pragma unroll
        for (int q = 0; q < 4; ++q) {
            const float4 tv = *reinterpret_cast<const float4*>(ts + q * 4);
            p += c4[q].x * tv.x + c4[q].y * tv.y + c4[q].z * tv.z + c4[q].w * tv.w;
        }
#pragma unroll
        for (int off = 32; off >= 1; off >>= 1) p += __shfl_xor(p, off);
        if (lane == 0) sc[w * 4 + o] = p;
    }
    __syncthreads();
    if (tid == 0) {
        float v1 = -INFINITY, v2 = -INFINITY; int i1 = 0, i2 = 0;
#pragma unroll
        for (int s = 0; s < 4 * PGRP; ++s) {   // selg sorted => ascending n
            const int n = selg[s >> 2] * 4 + (s & 3);
            const float v = sc[s];
            if (v > v1)      { v2 = v1; i2 = i1; v1 = v; i1 = n; }
            else if (v > v2) { v2 = v; i2 = n; }
        }
        sel[0] = i1; sel[1] = i2;
    }
    __syncthreads();
#pragma unroll
    for (int q = 0; q < 2; ++q) {
        const int src = sel[q];
        const float4 v = *reinterpret_cast<const float4*>(
            &t_s[(size_t)src * D_S + tid * 4]);
        *reinterpret_cast<float4*>(
            &out[((size_t)row * KSEL + q) * D_S + tid * 4]) = v;
    }
}

// ---------------------------------------------------------------------------
extern "C" void kernel_launch(void* const* d_in, const int* in_sizes, int n_in,
                              void* d_out, int out_size, void* d_ws, size_t ws_size,
                              hipStream_t stream) {
    const float* srt      = (const float*)d_in[0];  // [8192,1024]
    const float* comments = (const float*)d_in[1];  // [4096,768]
    const float* Wc       = (const float*)d_in[2];  // [768,1024]
    const float* bc       = (const float*)d_in[3];  // [1024]
    const float* Ws       = (const float*)d_in[4];  // [1024,1024]
    const float* bs       = (const float*)d_in[5];  // [1024]
    float* out = (float*)d_out;

    // base workspace layout
    char* p = (char*)d_ws;
    float* t_c = (float*)p;          p += (size_t)B_C * D_S * 4;     // 16 MB
    float* t_s = (float*)p;          p += (size_t)N_SRT * D_S * 4;   // 32 MB
    unsigned short* tc_h = (unsigned short*)p; p += (size_t)B_C * D_S * 2;    // 8 MB
    unsigned short* ts_h = (unsigned short*)p; p += (size_t)N_SRT * D_S * 2;  // 16 MB
    float* part = (float*)p;         p += (size_t)B_C * NGRP * 2;    // part in G's old slot
    p += (size_t)B_C * PGRP * 4;
    p += (size_t)B_C * KSEL * 4;

    // fp16 2-plane workspace (appended; ~53.4 MB)
    _Float16* actS = (_Float16*)p; p += 2 * (size_t)N_SRT * D_S * 2; // 33.5 MB
    _Float16* actC = (_Float16*)p; p += 2 * (size_t)B_C * D_C * 2;   // 12.6 MB
    _Float16* wtS  = (_Float16*)p; p += 2 * (size_t)D_S * D_S * 2;   // 4.2 MB
    _Float16* wtC  = (_Float16*)p; p += 2 * (size_t)D_S * D_C * 2;   // 3.1 MB
    const size_t required = (size_t)(p - (char*)d_ws);

    if (ws_size >= required) {
        // --- scaled fp16x3 MFMA transform path ---
        split_all<<<NS_ACT + 448, 256, 0, stream>>>(
            srt, comments, actS, actC, Ws, wtS, Wc, wtC);

        transform_mfma_all<<<512 + 256, 256, 0, stream>>>(
            actS, wtS, bs, t_s, ts_h,
            actC, wtC, bc, t_c, tc_h);
    } else {
        // --- fallback: round-5 verified fp32 VALU path ---
        transform_fused<<<NB0 + NB1, 256, 0, stream>>>(
            comments, Wc, bc, t_c, tc_h,
            srt,      Ws, bs, t_s, ts_h);
    }

    scores_filter<<<512, 512, 0, stream>>>(ts_h, tc_h, part);
    refine_gather<<<B_C, 256, 0, stream>>>(t_c, t_s, part, out);
}

// Round 20
// 205.119 us; speedup vs baseline: 1.1764x; 1.0583x over previous
//
#include <hip/hip_runtime.h>
#include <math.h>

#define B_C   4096   // comments
#define N_SRT 8192   // srt rows
#define D_C   768
#define D_S   1024
#define KSEL  2
#define NGRP  (N_SRT / 4)   // 2048 groups of 4 consecutive srt rows
#define PGRP  4             // groups refined per comment row (16 candidates)

typedef float    f32x4  __attribute__((ext_vector_type(4)));
typedef short    short8 __attribute__((ext_vector_type(8)));
typedef _Float16 half8  __attribute__((ext_vector_type(8)));

__device__ inline unsigned short f2bf(float f) {           // RTNE float->bf16
    unsigned u = __float_as_uint(f);
    u += 0x7FFF + ((u >> 16) & 1);
    return (unsigned short)(u >> 16);
}
__device__ inline float bf2f(unsigned short h) {
    return __uint_as_float(((unsigned)h) << 16);
}

#define GLOAD_LDS16(gsrc, ldst)                                                     \
    __builtin_amdgcn_global_load_lds(                                               \
        (const __attribute__((address_space(1))) void*)(gsrc),                      \
        (__attribute__((address_space(3))) void*)(ldst), 16, 0, 0)

// counted-vmcnt barrier pieces
#define WAIT_VM4  asm volatile("s_waitcnt vmcnt(4)" ::: "memory")
#define WAIT_VM0  asm volatile("s_waitcnt vmcnt(0)" ::: "memory")
#define WAIT_LGKM asm volatile("s_waitcnt lgkmcnt(0)" ::: "memory")

// ---------------------------------------------------------------------------
// split_all: act split + weight split in ONE launch (round-16 verified).
// ---------------------------------------------------------------------------
#define NS_ACT ((N_SRT * D_S / 8 + B_C * D_C / 8) / 256)   // 5632

__global__ __launch_bounds__(256)
void split_all(const float* __restrict__ srt, const float* __restrict__ com,
               _Float16* __restrict__ pS, _Float16* __restrict__ pC,
               const float* __restrict__ Ws, _Float16* __restrict__ WtS,
               const float* __restrict__ Wc, _Float16* __restrict__ WtC) {
    __shared__ float t[64][65];
    if ((int)blockIdx.x < NS_ACT) {
        const int g = blockIdx.x * 256 + threadIdx.x;
        const int E0 = N_SRT * D_S / 8;
        const float* src;
        _Float16* dst;
        size_t stride;
        if (g < E0) {
            src = srt + (size_t)g * 8; dst = pS + (size_t)g * 8;
            stride = (size_t)N_SRT * D_S;
        } else {
            const int g2 = g - E0;
            src = com + (size_t)g2 * 8; dst = pC + (size_t)g2 * 8;
            stride = (size_t)B_C * D_C;
        }
        const float4 a = *reinterpret_cast<const float4*>(src);
        const float4 b = *reinterpret_cast<const float4*>(src + 4);
        const float x[8] = {a.x, a.y, a.z, a.w, b.x, b.y, b.z, b.w};
        half8 hv, mv;
#pragma unroll
        for (int j = 0; j < 8; ++j) {
            const _Float16 h = (_Float16)x[j];
            const float    r = x[j] - (float)h;          // exact
            hv[j] = h; mv[j] = (_Float16)(r * 2048.0f);
        }
        *reinterpret_cast<half8*>(dst)          = hv;
        *reinterpret_cast<half8*>(dst + stride) = mv;
    } else {
        const int bb = (int)blockIdx.x - NS_ACT;
        const bool p1 = bb >= 256;
        const int  b  = p1 ? bb - 256 : bb;
        const float* __restrict__ W = p1 ? Wc : Ws;
        _Float16* __restrict__ Wt   = p1 ? WtC : WtS;
        const int K  = p1 ? D_C : D_S;
        const int n0 = (b & 15) * 64, k0 = (b >> 4) * 64;

        const int tid = threadIdx.x;
        const int c = tid & 63, rq = tid >> 6;
#pragma unroll
        for (int j = 0; j < 16; ++j) {
            const int kr = rq * 16 + j;
            t[kr][c] = W[(size_t)(k0 + kr) * D_S + n0 + c];
        }
        __syncthreads();
        const size_t PS = (size_t)K * D_S;
#pragma unroll
        for (int j = 0; j < 16; ++j) {
            const int nr = rq * 16 + j;
            const float xs = t[c][nr] * 32768.0f;        // exact (pow2 scale)
            const _Float16 h = (_Float16)xs;
            const float    r = xs - (float)h;            // exact
            const size_t o = (size_t)(n0 + nr) * K + k0 + c;
            Wt[o]      = h;
            Wt[o + PS] = (_Float16)(r * 2048.0f);
        }
    }
}

// ---------------------------------------------------------------------------
// transform_mfma_all (round-20: 1.5-buffered chunk fusion).
// r13's chunk-fused fp16x3 with the act planes SINGLE-buffered: all act
// fragment reads complete at chunk start (lgkm(0)+barrier), so A(c+1) can
// restage into the same buffer mid-chunk while 48 MFMAs run on registers.
// W stays double-buffered. LDS 64->48KB => 3 blocks/CU (VGPR 160 -> 12
// waves/CU) while keeping 48 MFMA per barrier-group.
// Schedule/chunk: [bar] 16 ds_reads -> lgkm(0) -> bar -> stage A(c+1)+
// W(c+1,~cur) -> MFMA x48 -> vmcnt(0) -> bar. Hazards: A-overwrite issued
// only after all waves' reads retired; stages drained before next reads.
// ---------------------------------------------------------------------------
__global__ __launch_bounds__(256)
void transform_mfma_all(const _Float16* __restrict__ actS,
                        const _Float16* __restrict__ wtS,
                        const float* __restrict__ bS,
                        float* __restrict__ CS, unsigned short* __restrict__ HS,
                        const _Float16* __restrict__ actC,
                        const _Float16* __restrict__ wtC,
                        const float* __restrict__ bC,
                        float* __restrict__ CC, unsigned short* __restrict__ HC) {
    __shared__ __align__(16) _Float16 sW[2][2][128 * 32];  // [buf][plane] 32KB
    __shared__ __align__(16) _Float16 sAp[2][128 * 32];    // [plane] single 16KB
    const int tid  = threadIdx.x;
    const int lane = tid & 63;
    const int w    = tid >> 6;
    const int lr   = lane & 15, lg = lane >> 4;
    const int wn   = w & 1, wc = w >> 1;

    const int hw = blockIdx.x;
    int lgid, seg;
    if (hw < 512) { seg = 0; lgid = (hw & 7) * 64 + (hw >> 3); }
    else          { const int h2 = hw - 512; seg = 1; lgid = (h2 & 7) * 32 + (h2 >> 3); }

    const _Float16* __restrict__ actP = seg ? actC : actS;
    const _Float16* __restrict__ wtP  = seg ? wtC  : wtS;
    const float* __restrict__ bias    = seg ? bC   : bS;
    float* __restrict__ C             = seg ? CC   : CS;
    unsigned short* __restrict__ H    = seg ? HC   : HS;
    const int K   = seg ? D_C : D_S;
    const int NC  = seg ? (D_C / 32) : (D_S / 32);    // 24 : 32 chunks
    const size_t aps = seg ? (size_t)B_C * D_C : (size_t)N_SRT * D_S;
    const size_t wps = (size_t)D_S * K;

    const int bn = (lgid & 7) * 128;
    const int bm = (lgid >> 3) * 128;

    const f32x4 vzero = {0.f, 0.f, 0.f, 0.f};
    f32x4 acc[4][4];
#pragma unroll
    for (int i = 0; i < 4; ++i)
#pragma unroll
        for (int j = 0; j < 4; ++j) acc[i][j] = vzero;

    auto stageW = [&](int buf, int c) {    // 4 gload_lds / thread
        const int kb = c * 32;
#pragma unroll
        for (int i = 0; i < 2; ++i) {
            const int idx = tid + i * 256;
            const int r   = idx >> 2;
            const int sw  = ((idx & 3) ^ ((r >> 1) & 3)) * 8;
            const size_t wo = (size_t)(bn + r) * K + kb + sw;
            GLOAD_LDS16(wtP + wo,       (char*)&sW[buf][0][0] + idx * 16);
            GLOAD_LDS16(wtP + wps + wo, (char*)&sW[buf][1][0] + idx * 16);
        }
    };
    auto stageA = [&](int c) {             // 4 gload_lds / thread
        const int kb = c * 32;
#pragma unroll
        for (int i = 0; i < 2; ++i) {
            const int idx = tid + i * 256;
            const int r   = idx >> 2;
            const int sw  = ((idx & 3) ^ ((r >> 1) & 3)) * 8;
            const size_t ao = (size_t)(bm + r) * K + kb + sw;
            GLOAD_LDS16(actP + ao,       (char*)&sAp[0][0] + idx * 16);
            GLOAD_LDS16(actP + aps + ao, (char*)&sAp[1][0] + idx * 16);
        }
    };

    stageW(0, 0);
    stageA(0);
    WAIT_VM0;
    __builtin_amdgcn_s_barrier();

    for (int c = 0; c < NC; ++c) {
        const int cur = c & 1;

        // ---- read all fragments for this chunk ----
        half8 a0[4], a1[4], b0[4], b1[4], b0s[4];
#pragma unroll
        for (int t4 = 0; t4 < 4; ++t4) {
            const int ra = wn * 64 + t4 * 16 + lr;
            const int oa = ra * 64 + ((lg ^ ((ra >> 1) & 3)) * 16);
            a0[t4] = *(const half8*)((const char*)&sW[cur][0][0] + oa);
            a1[t4] = *(const half8*)((const char*)&sW[cur][1][0] + oa);
            const int rb = wc * 64 + t4 * 16 + lr;
            const int ob = rb * 64 + ((lg ^ ((rb >> 1) & 3)) * 16);
            b0[t4] = *(const half8*)((const char*)&sAp[0][0] + ob);
            b1[t4] = *(const half8*)((const char*)&sAp[1][0] + ob);
            b0s[t4] = b0[t4] * (_Float16)2048.0f;    // exact pow2
        }
        WAIT_LGKM;                         // my reads retired
        __builtin_amdgcn_s_barrier();      // ALL waves' reads retired

        // ---- restage (A into same buffer; W into ~cur) ----
        if (c + 1 < NC) { stageA(c + 1); stageW(cur ^ 1, c + 1); }

        __builtin_amdgcn_s_setprio(1);
#pragma unroll
        for (int i = 0; i < 4; ++i)
#pragma unroll
            for (int j = 0; j < 4; ++j) {
                acc[i][j] = __builtin_amdgcn_mfma_f32_16x16x32_f16(
                    a0[i], b0s[j], acc[i][j], 0, 0, 0);   // hh (2^26)
                acc[i][j] = __builtin_amdgcn_mfma_f32_16x16x32_f16(
                    a0[i], b1[j],  acc[i][j], 0, 0, 0);   // hm (2^26)
                acc[i][j] = __builtin_amdgcn_mfma_f32_16x16x32_f16(
                    a1[i], b0[j],  acc[i][j], 0, 0, 0);   // mh (2^26)
            }
        __builtin_amdgcn_s_setprio(0);

        WAIT_VM0;                          // stages landed
        __builtin_amdgcn_s_barrier();      // next chunk may read
    }

    const float s2 = 1.4901161193847656e-8f;    // 2^-26
#pragma unroll
    for (int i = 0; i < 4; ++i) {
        const int n = bn + wn * 64 + i * 16 + lg * 4;
        const f32x4 bb = *reinterpret_cast<const f32x4*>(&bias[n]);
#pragma unroll
        for (int j = 0; j < 4; ++j) {
            const int m = bm + wc * 64 + j * 16 + lr;
            f32x4 o;
#pragma unroll
            for (int q = 0; q < 4; ++q)
                o[q] = fmaxf(fmaf(acc[i][j][q], s2, bb[q]), 0.f);
            *reinterpret_cast<f32x4*>(&C[(size_t)m * D_S + n]) = o;
            ushort4 hh;
            hh.x = f2bf(o[0]); hh.y = f2bf(o[1]);
            hh.z = f2bf(o[2]); hh.w = f2bf(o[3]);
            *reinterpret_cast<ushort4*>(&H[(size_t)m * D_S + n]) = hh;
        }
    }
}

// ---------------------------------------------------------------------------
// FALLBACK (round-5 verified): fused fp32 VALU transforms (ws too small).
// ---------------------------------------------------------------------------
#define NB0 ((B_C / 128) * (D_S / 128))     // 256
#define NB1 ((N_SRT / 128) * (D_S / 128))   // 512

__global__ __launch_bounds__(256)
void transform_fused(const float* __restrict__ A0, const float* __restrict__ W0,
                     const float* __restrict__ b0, float* __restrict__ C0,
                     unsigned short* __restrict__ H0,
                     const float* __restrict__ A1, const float* __restrict__ W1,
                     const float* __restrict__ b1, float* __restrict__ C1,
                     unsigned short* __restrict__ H1) {
    __shared__ __align__(16) float As[2][128][16];
    __shared__ __align__(16) float Bs[2][2048];

    const bool p1 = (int)blockIdx.x >= NB0;
    const int  b  = p1 ? (int)blockIdx.x - NB0 : (int)blockIdx.x;
    const float* __restrict__ A = p1 ? A1 : A0;
    const float* __restrict__ W = p1 ? W1 : W0;
    const float* __restrict__ bias = p1 ? b1 : b0;
    float* __restrict__ C = p1 ? C1 : C0;
    unsigned short* __restrict__ H = p1 ? H1 : H0;
    const int K = p1 ? D_S : D_C;

    const int bn = (b & 7) * 128;
    const int bm = (b >> 3) * 128;

    const int tid = threadIdx.x;
    const int tx = tid & 15, ty = tid >> 4;

    int a_off[2], w_off[2];
#pragma unroll
    for (int i = 0; i < 2; ++i) {
        const int idx = tid + i * 256;
        const int r = idx >> 2, q = idx & 3;
        a_off[i] = r * K + (q ^ ((r >> 3) & 3)) * 4;
        const int s = idx & 63;
        const int kloc = 2 * (idx >> 6) + ((s >> 4) & 1);
        const int cb   = 2 * (s & 15) + (s >> 5);
        w_off[i] = kloc * D_S + cb * 4;
    }

#define STAGE(bufi, k0)                                                        \
    {                                                                          \
        _Pragma("unroll")                                                      \
        for (int i = 0; i < 2; ++i) {                                          \
            const int idx = tid + i * 256;                                     \
            GLOAD_LDS16(A + (size_t)bm * K + (k0) + a_off[i],                  \
                        (char*)&As[bufi][0][0] + idx * 16);                    \
            GLOAD_LDS16(W + (size_t)(k0) * D_S + bn + w_off[i],                \
                        (char*)&Bs[bufi][0] + idx * 16);                       \
        }                                                                      \
    }

    float acc[8][8] = {};

    STAGE(0, 0);
    __syncthreads();

    const int nk = K / 16;
    for (int t = 0; t < nk; ++t) {
        const int cur = t & 1;
        if (t + 1 < nk) STAGE(t & 1 ? 0 : 1, (t + 1) * 16);

        const float* __restrict__ Bf = &Bs[cur][0];
#pragma unroll
        for (int kq = 0; kq < 4; ++kq) {
            f32x4 a4[8];
#pragma unroll
            for (int i = 0; i < 8; ++i)
                a4[i] = *reinterpret_cast<const f32x4*>(
                    &As[cur][ty * 8 + i][(kq ^ (ty & 3)) * 4]);
#pragma unroll
            for (int k2 = 0; k2 < 4; ++k2) {
                const int k = kq * 4 + k2;
                const int boff = (k >> 1) * 256 + (tx + ((k & 1) << 4)) * 4;
                const f32x4 bx = *reinterpret_cast<const f32x4*>(Bf + boff);
                const f32x4 by = *reinterpret_cast<const f32x4*>(Bf + boff + 128);
                const float bv[8] = {bx[0], bx[1], bx[2], bx[3], by[0], by[1], by[2], by[3]};
#pragma unroll
                for (int i = 0; i < 8; ++i) {
                    const float av = a4[i][k2];
#pragma unroll
                    for (int j = 0; j < 8; ++j)
                        acc[i][j] = fmaf(av, bv[j], acc[i][j]);
                }
            }
        }
        __syncthreads();
    }
#undef STAGE

    const f32x4 g0 = *reinterpret_cast<const f32x4*>(&bias[bn + tx * 8]);
    const f32x4 g1 = *reinterpret_cast<const f32x4*>(&bias[bn + tx * 8 + 4]);
#pragma unroll
    for (int i = 0; i < 8; ++i) {
        const int m = bm + ty * 8 + i;
        const int n = bn + tx * 8;
        f32x4 o0, o1;
#pragma unroll
        for (int j = 0; j < 4; ++j) {
            o0[j] = fmaxf(acc[i][j]     + g0[j], 0.f);
            o1[j] = fmaxf(acc[i][j + 4] + g1[j], 0.f);
        }
        *reinterpret_cast<f32x4*>(&C[(size_t)m * D_S + n])     = o0;
        *reinterpret_cast<f32x4*>(&C[(size_t)m * D_S + n + 4]) = o1;
        short8 h;
#pragma unroll
        for (int j = 0; j < 4; ++j) {
            h[j]     = (short)f2bf(o0[j]);
            h[j + 4] = (short)f2bf(o1[j]);
        }
        *reinterpret_cast<short8*>(&H[(size_t)m * D_S + n]) = h;
    }
}

// ---------------------------------------------------------------------------
// Kernel 2: bf16 MFMA score filter — round-15/16 verified. Unchanged.
// ---------------------------------------------------------------------------
__global__ __launch_bounds__(512)
void scores_filter(const unsigned short* __restrict__ TSh,
                   const unsigned short* __restrict__ TCh,
                   float* __restrict__ part) {     // [B_C][64] float4 entries
    __shared__ __align__(16) unsigned short sA[2][2][128 * 64];  // [parity][half]
    __shared__ __align__(16) unsigned short sB[2][2][128 * 64];
    const int tid  = threadIdx.x;
    const int lane = tid & 63;
    const int w    = tid >> 6;          // 0..7
    const int mw   = w >> 2;            // A(srt) half: 0..1
    const int nw   = w & 3;             // B(c) quarter: 0..3
    const int bh   = nw >> 1;           // B half this wave reads
    const int lr   = lane & 15, lg = lane >> 4;

    const int hw   = blockIdx.x;
    const int lgid = (hw & 7) * 64 + (hw >> 3);
    const int n0   = (lgid & 31) * 256;     // srt tile
    const int c0   = (lgid >> 5) * 256;     // comment tile

    const f32x4 vzero = {0.f, 0.f, 0.f, 0.f};
    f32x4 acc[8][4];
#pragma unroll
    for (int i = 0; i < 8; ++i)
#pragma unroll
        for (int j = 0; j < 4; ++j) acc[i][j] = vzero;

    auto stageHalf = [&](unsigned short* ldsbase, const unsigned short* grow0,
                         int kb) {
#pragma unroll
        for (int i = 0; i < 2; ++i) {
            const int idx = tid + i * 512;
            const int r   = idx >> 3;
            const int sw  = ((idx & 7) ^ (r & 7)) * 8;
            GLOAD_LDS16(grow0 + (size_t)r * D_S + kb + sw,
                        (char*)ldsbase + idx * 16);
        }
    };

    const unsigned short* TS0 = TSh + (size_t)n0 * D_S;
    const unsigned short* TS1 = TSh + (size_t)(n0 + 128) * D_S;
    const unsigned short* TC0 = TCh + (size_t)c0 * D_S;
    const unsigned short* TC1 = TCh + (size_t)(c0 + 128) * D_S;

    stageHalf(&sA[0][0][0], TS0, 0);
    stageHalf(&sA[0][1][0], TS1, 0);
    stageHalf(&sB[0][0][0], TC0, 0);
    stageHalf(&sB[0][1][0], TC1, 0);
    stageHalf(&sB[1][0][0], TC0, 64);
    stageHalf(&sB[1][1][0], TC1, 64);
    WAIT_VM4;
    __builtin_amdgcn_s_barrier();

    const int NITER = D_S / 128;        // 8 iterations, 2 K-steps each
    for (int t = 0; t < NITER; ++t) {
        const bool nl = (t + 1 < NITER);

#pragma unroll
        for (int par = 0; par < 2; ++par) {
            short8 bfr[4][2];
#pragma unroll
            for (int ph = 0; ph < 4; ++ph) {
                short8 afr[2][2];
                if (ph == 0) {
#pragma unroll
                    for (int j = 0; j < 4; ++j) {
                        const int rb = (nw & 1) * 64 + j * 16 + lr;
#pragma unroll
                        for (int kk = 0; kk < 2; ++kk)
                            bfr[j][kk] = *(const short8*)(
                                (const char*)&sB[par][bh][0] + rb * 128 +
                                (((kk * 4 + lg) ^ (rb & 7)) * 16));
                    }
                }
#pragma unroll
                for (int ii = 0; ii < 2; ++ii) {
                    const int ra = (ph * 2 + ii) * 16 + lr;
#pragma unroll
                    for (int kk = 0; kk < 2; ++kk)
                        afr[ii][kk] = *(const short8*)(
                            (const char*)&sA[par][mw][0] + ra * 128 +
                            (((kk * 4 + lg) ^ (ra & 7)) * 16));
                }
                if (par == 0) {
                    if (ph == 0)            stageHalf(&sA[1][0][0], TS0, (2*t+1)*64);
                    else if (ph == 1)       stageHalf(&sA[1][1][0], TS1, (2*t+1)*64);
                    else if (ph == 2) { if (nl) stageHalf(&sB[0][0][0], TC0, (2*t+2)*64); }
                    else              { if (nl) stageHalf(&sB[0][1][0], TC1, (2*t+2)*64); }
                } else {
                    if (ph == 0)      { if (nl) stageHalf(&sA[0][0][0], TS0, (2*t+2)*64); }
                    else if (ph == 1) { if (nl) stageHalf(&sA[0][1][0], TS1, (2*t+2)*64); }
                    else if (ph == 2) { if (nl) stageHalf(&sB[1][0][0], TC0, (2*t+3)*64); }
                    else              { if (nl) stageHalf(&sB[1][1][0], TC1, (2*t+3)*64); }
                }
                if (ph == 3) { if (nl) { WAIT_VM4; } else { WAIT_VM0; } }
                __builtin_amdgcn_s_barrier();
                WAIT_LGKM;
                __builtin_amdgcn_s_setprio(1);
#pragma unroll
                for (int ii = 0; ii < 2; ++ii)
#pragma unroll
                    for (int j = 0; j < 4; ++j)
#pragma unroll
                        for (int kk = 0; kk < 2; ++kk)
                            acc[ph * 2 + ii][j] = __builtin_amdgcn_mfma_f32_16x16x32_bf16(
                                afr[ii][kk], bfr[j][kk], acc[ph * 2 + ii][j], 0, 0, 0);
                __builtin_amdgcn_s_setprio(0);
                __builtin_amdgcn_s_barrier();
            }
        }
    }

    // epilogue: per-(c, half) top-2 -> part (round-16 verified)
    const int gbase = (n0 >> 2) + mw * 32;
#pragma unroll
    for (int j = 0; j < 4; ++j) {
        float v1 = -INFINITY, v2 = -INFINITY;
        int   g1 = 0, g2 = 0;
#pragma unroll
        for (int i = 0; i < 8; ++i) {
            const f32x4 v = acc[i][j];
            const float m = fmaxf(fmaxf(v.x, v.y), fmaxf(v.z, v.w));
            const int g = gbase + i * 4 + lg;
            if (m > v1)      { v2 = v1; g2 = g1; v1 = m; g1 = g; }
            else if (m > v2) { v2 = m; g2 = g; }
        }
#pragma unroll
        for (int off = 16; off <= 32; off <<= 1) {
            const float ov1 = __shfl_xor(v1, off);
            const int   og1 = __shfl_xor(g1, off);
            const float ov2 = __shfl_xor(v2, off);
            const int   og2 = __shfl_xor(g2, off);
            if (ov1 > v1 || (ov1 == v1 && og1 < g1)) { v2 = v1; g2 = g1; v1 = ov1; g1 = og1; }
            else if (ov1 > v2 || (ov1 == v2 && og1 < g2)) { v2 = ov1; g2 = og1; }
            if (ov2 > v1 || (ov2 == v1 && og2 < g1)) { v2 = v1; g2 = g1; v1 = ov2; g1 = og2; }
            else if (ov2 > v2 || (ov2 == v2 && og2 < g2)) { v2 = ov2; g2 = og2; }
        }
        if (lg == 0) {
            const int c = c0 + nw * 64 + j * 16 + lr;
            const int blk2 = (lgid & 31) * 2 + mw;
            f32x4 e;
            e[0] = v1; e[1] = __int_as_float(g1);
            e[2] = v2; e[3] = __int_as_float(g2);
            *reinterpret_cast<f32x4*>(&part[((size_t)c * 64 + blk2) * 4]) = e;
        }
    }
}

// ---------------------------------------------------------------------------
// Kernel 3: fused merge + refine + gather (round-17 verified). Unchanged.
// ---------------------------------------------------------------------------
__global__ __launch_bounds__(256)
void refine_gather(const float* __restrict__ t_c, const float* __restrict__ t_s,
                   const float* __restrict__ part, float* __restrict__ out) {
    __shared__ float tc[D_S];
    __shared__ float sc[4 * PGRP];
    __shared__ int   selg[PGRP];
    __shared__ int   sel[2];
    const int row = blockIdx.x;
    const int tid = threadIdx.x;
    *reinterpret_cast<float4*>(&tc[tid * 4]) =
        *reinterpret_cast<const float4*>(&t_c[(size_t)row * D_S + tid * 4]);
    const int w = tid >> 6, lane = tid & 63;

    if (w == 0) {   // merge: lane holds one part entry (2 candidates)
        const f32x4 e = *reinterpret_cast<const f32x4*>(
            &part[((size_t)row * 64 + lane) * 4]);
        const float v[2]  = {e[0], e[2]};
        const int   gi[2] = {__float_as_int(e[1]), __float_as_int(e[3])};
        float pv = INFINITY; int pi = -1;
        int gl[PGRP];
#pragma unroll
        for (int k = 0; k < PGRP; ++k) {
            float bv = -INFINITY; int bi = 0x7FFFFFFF;
#pragma unroll
            for (int s = 0; s < 2; ++s) {
                const bool after  = (v[s] < pv) || (v[s] == pv && gi[s] > pi);
                const bool before = (v[s] > bv) || (v[s] == bv && gi[s] < bi);
                if (after && before) { bv = v[s]; bi = gi[s]; }
            }
#pragma unroll
            for (int off = 32; off >= 1; off >>= 1) {
                const float ov = __shfl_xor(bv, off);
                const int   oi = __shfl_xor(bi, off);
                if ((ov > bv) || (ov == bv && oi < bi)) { bv = ov; bi = oi; }
            }
            gl[k] = bi; pv = bv; pi = bi;
        }
#pragma unroll
        for (int a = 0; a < PGRP; ++a)
#pragma unroll
            for (int b2 = 0; b2 < PGRP - 1; ++b2)
                if (gl[b2] > gl[b2 + 1]) { int t = gl[b2]; gl[b2] = gl[b2 + 1]; gl[b2 + 1] = t; }
        if (lane == 0) {
#pragma unroll
            for (int k = 0; k < PGRP; ++k) selg[k] = gl[k];
        }
    }
    __syncthreads();

    float4 c4[4];
#pragma unroll
    for (int q = 0; q < 4; ++q)
        c4[q] = *reinterpret_cast<const float4*>(&tc[lane * 16 + q * 4]);
    const int g = selg[w];               // one group per wave
#pragma unroll
    for (int o = 0; o < 4; ++o) {
        const int n = g * 4 + o;
        const float* ts = t_s + (size_t)n * D_S + lane * 16;
        float p = 0.f;
#pragma unroll
        for (int q = 0; q < 4; ++q) {
            const float4 tv = *reinterpret_cast<const float4*>(ts + q * 4);
            p += c4[q].x * tv.x + c4[q].y * tv.y + c4[q].z * tv.z + c4[q].w * tv.w;
        }
#pragma unroll
        for (int off = 32; off >= 1; off >>= 1) p += __shfl_xor(p, off);
        if (lane == 0) sc[w * 4 + o] = p;
    }
    __syncthreads();
    if (tid == 0) {
        float v1 = -INFINITY, v2 = -INFINITY; int i1 = 0, i2 = 0;
#pragma unroll
        for (int s = 0; s < 4 * PGRP; ++s) {   // selg sorted => ascending n
            const int n = selg[s >> 2] * 4 + (s & 3);
            const float v = sc[s];
            if (v > v1)      { v2 = v1; i2 = i1; v1 = v; i1 = n; }
            else if (v > v2) { v2 = v; i2 = n; }
        }
        sel[0] = i1; sel[1] = i2;
    }
    __syncthreads();
#pragma unroll
    for (int q = 0; q < 2; ++q) {
        const int src = sel[q];
        const float4 v = *reinterpret_cast<const float4*>(
            &t_s[(size_t)src * D_S + tid * 4]);
        *reinterpret_cast<float4*>(
            &out[((size_t)row * KSEL + q) * D_S + tid * 4]) = v;
    }
}

// ---------------------------------------------------------------------------
extern "C" void kernel_launch(void* const* d_in, const int* in_sizes, int n_in,
                              void* d_out, int out_size, void* d_ws, size_t ws_size,
                              hipStream_t stream) {
    const float* srt      = (const float*)d_in[0];  // [8192,1024]
    const float* comments = (const float*)d_in[1];  // [4096,768]
    const float* Wc       = (const float*)d_in[2];  // [768,1024]
    const float* bc       = (const float*)d_in[3];  // [1024]
    const float* Ws       = (const float*)d_in[4];  // [1024,1024]
    const float* bs       = (const float*)d_in[5];  // [1024]
    float* out = (float*)d_out;

    // base workspace layout
    char* p = (char*)d_ws;
    float* t_c = (float*)p;          p += (size_t)B_C * D_S * 4;     // 16 MB
    float* t_s = (float*)p;          p += (size_t)N_SRT * D_S * 4;   // 32 MB
    unsigned short* tc_h = (unsigned short*)p; p += (size_t)B_C * D_S * 2;    // 8 MB
    unsigned short* ts_h = (unsigned short*)p; p += (size_t)N_SRT * D_S * 2;  // 16 MB
    float* part = (float*)p;         p += (size_t)B_C * NGRP * 2;    // part in G's old slot
    p += (size_t)B_C * PGRP * 4;
    p += (size_t)B_C * KSEL * 4;

    // fp16 2-plane workspace (appended; ~53.4 MB)
    _Float16* actS = (_Float16*)p; p += 2 * (size_t)N_SRT * D_S * 2; // 33.5 MB
    _Float16* actC = (_Float16*)p; p += 2 * (size_t)B_C * D_C * 2;   // 12.6 MB
    _Float16* wtS  = (_Float16*)p; p += 2 * (size_t)D_S * D_S * 2;   // 4.2 MB
    _Float16* wtC  = (_Float16*)p; p += 2 * (size_t)D_S * D_C * 2;   // 3.1 MB
    const size_t required = (size_t)(p - (char*)d_ws);

    if (ws_size >= required) {
        // --- scaled fp16x3 MFMA transform path ---
        split_all<<<NS_ACT + 448, 256, 0, stream>>>(
            srt, comments, actS, actC, Ws, wtS, Wc, wtC);

        transform_mfma_all<<<512 + 256, 256, 0, stream>>>(
            actS, wtS, bs, t_s, ts_h,
            actC, wtC, bc, t_c, tc_h);
    } else {
        // --- fallback: round-5 verified fp32 VALU path ---
        transform_fused<<<NB0 + NB1, 256, 0, stream>>>(
            comments, Wc, bc, t_c, tc_h,
            srt,      Ws, bs, t_s, ts_h);
    }

    scores_filter<<<512, 512, 0, stream>>>(ts_h, tc_h, part);
    refine_gather<<<B_C, 256, 0, stream>>>(t_c, t_s, part, out);
}